// Round 1
// baseline (77.116 us; speedup 1.0000x reference)
//
#include <hip/hip_runtime.h>

// loss = sum_ij C[i,j] * (t[i] + t[j] - 2*G[i,j]) / (B * (n_pos + 1e-8))
//   t[k]  = sum_b P[b,k]^2
//   G[i,j]= sum_b P[b,i]*P[b,j]   (Gram of P columns)
//   n_pos = count(C > 0)

#define B_DIM 128
#define N_DIM 1024
#define TILE  64

__device__ double g_sum;
__device__ unsigned long long g_cnt;
__device__ float g_t[N_DIM];

// Kernel A: t[k] = sum_b P[b,k]^2 ; also zero the accumulators (safe: kernel B
// runs after A completes in stream order).
__global__ __launch_bounds__(256) void tsq_kernel(const float* __restrict__ P) {
    int k = blockIdx.x * 256 + threadIdx.x;
    if (k == 0) g_sum = 0.0;
    if (k == 1) g_cnt = 0ull;
    float s = 0.f;
#pragma unroll 8
    for (int b = 0; b < B_DIM; ++b) {
        float v = P[b * N_DIM + k];
        s = fmaf(v, v, s);
    }
    g_t[k] = s;
}

// Kernel B: one 64x64 tile of C per block; fused Gram + weighted reduction.
__global__ __launch_bounds__(256) void main_kernel(const float* __restrict__ P,
                                                   const float* __restrict__ C) {
    __shared__ float Pi[B_DIM][TILE];   // 32 KB: P columns i0..i0+63
    __shared__ float Pj[B_DIM][TILE];   // 32 KB: P columns j0..j0+63
    __shared__ double wsum[4];
    __shared__ int    wcnt[4];

    const int tj_blk = blockIdx.x & 15;   // N/TILE = 16
    const int ti_blk = blockIdx.x >> 4;
    const int i0 = ti_blk * TILE, j0 = tj_blk * TILE;
    const int tid = threadIdx.x;

    // Stage P panels via float4: 128*64/4 = 2048 float4 each, 8 per thread.
    const float4* P4 = (const float4*)P;
    float4* Pi4 = (float4*)&Pi[0][0];
    float4* Pj4 = (float4*)&Pj[0][0];
#pragma unroll
    for (int r = 0; r < 8; ++r) {
        int idx = r * 256 + tid;        // 0..2047
        int b   = idx >> 4;             // row (batch)
        int q   = idx & 15;             // float4 within row
        Pi4[idx] = P4[b * (N_DIM / 4) + (i0 >> 2) + q];
        Pj4[idx] = P4[b * (N_DIM / 4) + (j0 >> 2) + q];
    }
    __syncthreads();

    // 16x16 thread grid, each thread owns a 4x4 micro-tile of G.
    const int tx = tid & 15, ty = tid >> 4;
    float g00=0,g01=0,g02=0,g03=0, g10=0,g11=0,g12=0,g13=0,
          g20=0,g21=0,g22=0,g23=0, g30=0,g31=0,g32=0,g33=0;
#pragma unroll 4
    for (int b = 0; b < B_DIM; ++b) {
        float4 a = *(const float4*)&Pi[b][ty * 4];
        float4 c = *(const float4*)&Pj[b][tx * 4];
        g00 = fmaf(a.x, c.x, g00); g01 = fmaf(a.x, c.y, g01);
        g02 = fmaf(a.x, c.z, g02); g03 = fmaf(a.x, c.w, g03);
        g10 = fmaf(a.y, c.x, g10); g11 = fmaf(a.y, c.y, g11);
        g12 = fmaf(a.y, c.z, g12); g13 = fmaf(a.y, c.w, g13);
        g20 = fmaf(a.z, c.x, g20); g21 = fmaf(a.z, c.y, g21);
        g22 = fmaf(a.z, c.z, g22); g23 = fmaf(a.z, c.w, g23);
        g30 = fmaf(a.w, c.x, g30); g31 = fmaf(a.w, c.y, g31);
        g32 = fmaf(a.w, c.z, g32); g33 = fmaf(a.w, c.w, g33);
    }
    float gm[4][4] = {{g00,g01,g02,g03},{g10,g11,g12,g13},
                      {g20,g21,g22,g23},{g30,g31,g32,g33}};

    float ti[4], tj[4];
#pragma unroll
    for (int r = 0; r < 4; ++r) ti[r] = g_t[i0 + ty * 4 + r];
#pragma unroll
    for (int c = 0; c < 4; ++c) tj[c] = g_t[j0 + tx * 4 + c];

    float acc = 0.f;
    int   cnt = 0;
    const float4* C4 = (const float4*)C;
#pragma unroll
    for (int r = 0; r < 4; ++r) {
        float4 cv = C4[(size_t)(i0 + ty * 4 + r) * (N_DIM / 4) + (j0 >> 2) + tx];
        acc = fmaf(cv.x, ti[r] + tj[0] - 2.f * gm[r][0], acc);
        acc = fmaf(cv.y, ti[r] + tj[1] - 2.f * gm[r][1], acc);
        acc = fmaf(cv.z, ti[r] + tj[2] - 2.f * gm[r][2], acc);
        acc = fmaf(cv.w, ti[r] + tj[3] - 2.f * gm[r][3], acc);
        cnt += (cv.x > 0.f) + (cv.y > 0.f) + (cv.z > 0.f) + (cv.w > 0.f);
    }

    // Wave(64)-level shuffle reduction, then cross-wave via LDS.
#pragma unroll
    for (int off = 32; off > 0; off >>= 1) {
        acc += __shfl_down(acc, off);
        cnt += __shfl_down(cnt, off);
    }
    const int wave = tid >> 6, lane = tid & 63;
    if (lane == 0) { wsum[wave] = (double)acc; wcnt[wave] = cnt; }
    __syncthreads();
    if (tid == 0) {
        double s = wsum[0] + wsum[1] + wsum[2] + wsum[3];
        int    c = wcnt[0] + wcnt[1] + wcnt[2] + wcnt[3];
        atomicAdd(&g_sum, s);
        atomicAdd(&g_cnt, (unsigned long long)c);
    }
}

__global__ void fin_kernel(float* __restrict__ out) {
    double npos = (double)g_cnt;
    out[0] = (float)(g_sum / ((double)B_DIM * (npos + 1e-8)));
}

extern "C" void kernel_launch(void* const* d_in, const int* in_sizes, int n_in,
                              void* d_out, int out_size, void* d_ws, size_t ws_size,
                              hipStream_t stream) {
    const float* probs = (const float*)d_in[0];   // [128, 1024] fp32
    const float* co    = (const float*)d_in[1];   // [1024, 1024] fp32
    float* out = (float*)d_out;

    tsq_kernel<<<N_DIM / 256, 256, 0, stream>>>(probs);
    main_kernel<<<(N_DIM / TILE) * (N_DIM / TILE), 256, 0, stream>>>(probs, co);
    fin_kernel<<<1, 64, 0, stream>>>(out);
}

// Round 2
// 65.989 us; speedup vs baseline: 1.1686x; 1.1686x over previous
//
#include <hip/hip_runtime.h>

// loss = sum_ij C[i,j]*(t[i]+t[j]-2*G[i,j]) / (B*(n_pos+1e-8))
//   t[k]  = sum_b P[b,k]^2 ;  G = P^T P (Gram of P columns) ; n_pos = count(C>0)
//
// Single tile kernel: 256 blocks, one 64x64 tile of C each. Stages the two
// 128x64 P panels in LDS, computes t in-block from the staged panels (no
// separate kernel / global round-trip), 2x4 register micro-tile Gram,
// per-block partial sum+count -> d_ws; tiny reduce kernel finalizes.

#define B_DIM 128
#define N_DIM 1024
#define TILE  64

__global__ __launch_bounds__(512) void tile_kernel(const float* __restrict__ P,
                                                   const float* __restrict__ C,
                                                   double* __restrict__ psum,
                                                   unsigned* __restrict__ pcnt) {
    __shared__ float Pi[B_DIM][TILE];   // 32 KB
    __shared__ float Pj[B_DIM][TILE];   // 32 KB
    __shared__ float ts[2 * TILE];      // t for [i-cols | j-cols]
    __shared__ double wsum[8];
    __shared__ unsigned wcnt[8];

    const int tid = threadIdx.x;
    const int tj_blk = blockIdx.x & 15;         // N/TILE = 16
    const int ti_blk = blockIdx.x >> 4;
    const int i0 = ti_blk * TILE, j0 = tj_blk * TILE;

    // --- stage P panels: 2048 float4 each, 512 threads -> 4 per thread ---
    const float4* P4 = (const float4*)P;
    float4* Pi4 = (float4*)&Pi[0][0];
    float4* Pj4 = (float4*)&Pj[0][0];
#pragma unroll
    for (int r = 0; r < 4; ++r) {
        int idx = r * 512 + tid;                // 0..2047
        int b   = idx >> 4;                     // batch row
        int q   = idx & 15;                     // float4 within row
        Pi4[idx] = P4[b * (N_DIM / 4) + (i0 >> 2) + q];
        Pj4[idx] = P4[b * (N_DIM / 4) + (j0 >> 2) + q];
    }
    __syncthreads();

    // --- t for the 128 staged columns (threads 0..127, trivial) ---
    if (tid < 2 * TILE) {
        const float* col = (tid < TILE) ? &Pi[0][tid] : &Pj[0][tid - TILE];
        float s = 0.f;
#pragma unroll 8
        for (int b = 0; b < B_DIM; ++b) {
            float v = col[b * TILE];
            s = fmaf(v, v, s);
        }
        ts[tid] = s;
    }
    __syncthreads();

    // --- Gram micro-tile: 16x32 thread grid, 2 rows x 4 cols per thread ---
    const int tx = tid & 15;                    // j group (4 cols)
    const int ty = tid >> 4;                    // i group (2 rows), 0..31
    float g00=0,g01=0,g02=0,g03=0, g10=0,g11=0,g12=0,g13=0;
#pragma unroll 8
    for (int b = 0; b < B_DIM; ++b) {
        float2 a = *(const float2*)&Pi[b][ty * 2];
        float4 c = *(const float4*)&Pj[b][tx * 4];
        g00 = fmaf(a.x, c.x, g00); g01 = fmaf(a.x, c.y, g01);
        g02 = fmaf(a.x, c.z, g02); g03 = fmaf(a.x, c.w, g03);
        g10 = fmaf(a.y, c.x, g10); g11 = fmaf(a.y, c.y, g11);
        g12 = fmaf(a.y, c.z, g12); g13 = fmaf(a.y, c.w, g13);
    }
    float gm[2][4] = {{g00,g01,g02,g03},{g10,g11,g12,g13}};

    float ti[2], tj[4];
#pragma unroll
    for (int r = 0; r < 2; ++r) ti[r] = ts[ty * 2 + r];
#pragma unroll
    for (int c = 0; c < 4; ++c) tj[c] = ts[TILE + tx * 4 + c];

    // --- C tile read + weighted accumulate ---
    float acc = 0.f;
    unsigned cnt = 0;
    const float4* C4 = (const float4*)C;
#pragma unroll
    for (int r = 0; r < 2; ++r) {
        float4 cv = C4[(size_t)(i0 + ty * 2 + r) * (N_DIM / 4) + (j0 >> 2) + tx];
        acc = fmaf(cv.x, ti[r] + tj[0] - 2.f * gm[r][0], acc);
        acc = fmaf(cv.y, ti[r] + tj[1] - 2.f * gm[r][1], acc);
        acc = fmaf(cv.z, ti[r] + tj[2] - 2.f * gm[r][2], acc);
        acc = fmaf(cv.w, ti[r] + tj[3] - 2.f * gm[r][3], acc);
        cnt += (cv.x > 0.f) + (cv.y > 0.f) + (cv.z > 0.f) + (cv.w > 0.f);
    }

    // --- reduction: wave64 shuffle, then cross-wave via LDS ---
#pragma unroll
    for (int off = 32; off > 0; off >>= 1) {
        acc += __shfl_down(acc, off);
        cnt += __shfl_down(cnt, off);
    }
    const int wave = tid >> 6, lane = tid & 63;
    if (lane == 0) { wsum[wave] = (double)acc; wcnt[wave] = cnt; }
    __syncthreads();
    if (tid == 0) {
        double s = 0.0; unsigned c = 0;
#pragma unroll
        for (int w = 0; w < 8; ++w) { s += wsum[w]; c += wcnt[w]; }
        psum[blockIdx.x] = s;
        pcnt[blockIdx.x] = c;
    }
}

__global__ __launch_bounds__(256) void reduce_kernel(const double* __restrict__ psum,
                                                     const unsigned* __restrict__ pcnt,
                                                     float* __restrict__ out) {
    __shared__ double ws[4];
    __shared__ unsigned wc[4];
    const int tid = threadIdx.x;
    double s = psum[tid];
    unsigned c = pcnt[tid];
#pragma unroll
    for (int off = 32; off > 0; off >>= 1) {
        s += __shfl_down(s, off);
        c += __shfl_down(c, off);
    }
    const int wave = tid >> 6, lane = tid & 63;
    if (lane == 0) { ws[wave] = s; wc[wave] = c; }
    __syncthreads();
    if (tid == 0) {
        double st = ws[0] + ws[1] + ws[2] + ws[3];
        double ct = (double)(wc[0] + wc[1] + wc[2] + wc[3]);
        out[0] = (float)(st / ((double)B_DIM * (ct + 1e-8)));
    }
}

extern "C" void kernel_launch(void* const* d_in, const int* in_sizes, int n_in,
                              void* d_out, int out_size, void* d_ws, size_t ws_size,
                              hipStream_t stream) {
    const float* probs = (const float*)d_in[0];   // [128, 1024] fp32
    const float* co    = (const float*)d_in[1];   // [1024, 1024] fp32
    float* out = (float*)d_out;

    double*   psum = (double*)d_ws;                       // 256 * 8 B
    unsigned* pcnt = (unsigned*)((char*)d_ws + 256 * 8);  // 256 * 4 B

    tile_kernel<<<(N_DIM / TILE) * (N_DIM / TILE), 512, 0, stream>>>(probs, co, psum, pcnt);
    reduce_kernel<<<1, 256, 0, stream>>>(psum, pcnt, out);
}